// Round 14
// baseline (150.826 us; speedup 1.0000x reference)
//
#include <hip/hip_runtime.h>

#define IN_DIM 128
#define HEADS 4
#define OUT_DIM 32
#define NEG 0.2f

#define NPB 256        // nodes per bucket (bucket = dst >> 8)
#define NB_MAX 400     // max buckets (N=100000 -> 391)
#define EPB 8192       // edges per block in hist/bin kernels

typedef unsigned int uint;
typedef unsigned short ushort_t;
typedef short short8 __attribute__((ext_vector_type(8)));
typedef float f32x4 __attribute__((ext_vector_type(4)));
typedef uint u32x4 __attribute__((ext_vector_type(4)));

__device__ __forceinline__ uint bf16r(float f) {
    uint u = __float_as_uint(f);
    return (u + 0x7fffu + ((u >> 16) & 1u)) >> 16;   // RNE
}

// ---------------- proj body: 32 rows/wave, col-permuted wt ----------------
// wt row rho = nt*16+c holds W[:, 8c+nt]  =>  lane c's 8 accs are cols
// 8c..8c+7 (one 16B chunk) => feat stored as ONE dwordx4 per (node,r)
// instead of 64 scalar 2B stores per wave. Aggregate's chunk layout
// (chunk ll = cols 8ll..8ll+7, head ll>>2) matches EXACTLY -> agg unchanged.
__device__ __forceinline__ void proj_body(
    int pblk, const float* __restrict__ x, const ushort_t* __restrict__ wt,
    const ushort_t* __restrict__ wt2,
    ushort_t* __restrict__ feat16, float* __restrict__ el, float* __restrict__ er,
    int N)
{
    const int lane = threadIdx.x & 63;
    const int w    = threadIdx.x >> 6;
    const int rowbase = pblk * 128 + w * 32;   // 32 rows per wave
    const int c = lane & 15;
    const int g = lane >> 4;

    f32x4 acc0[8], acc1[8];
    #pragma unroll
    for (int nt = 0; nt < 8; ++nt) {
        acc0[nt] = (f32x4){0.f, 0.f, 0.f, 0.f};
        acc1[nt] = (f32x4){0.f, 0.f, 0.f, 0.f};
    }
    f32x4 acc8v0 = (f32x4){0.f, 0.f, 0.f, 0.f};   // el/er tile, rows 0..15
    f32x4 acc8v1 = (f32x4){0.f, 0.f, 0.f, 0.f};   // el/er tile, rows 16..31

    const int arow0 = rowbase + c;
    const int arow1 = rowbase + 16 + c;
    const int arow0c = (arow0 < N) ? arow0 : (N - 1);
    const int arow1c = (arow1 < N) ? arow1 : (N - 1);
    const float* xrow0 = x + (size_t)arow0c * 128 + g * 8;
    const float* xrow1 = x + (size_t)arow1c * 128 + g * 8;

    #pragma unroll
    for (int kk = 0; kk < 4; ++kk) {
        float4 a0 = *(const float4*)(xrow0 + kk * 32);
        float4 a1 = *(const float4*)(xrow0 + kk * 32 + 4);
        float4 b0 = *(const float4*)(xrow1 + kk * 32);
        float4 b1 = *(const float4*)(xrow1 + kk * 32 + 4);
        u32x4 au0, au1;
        au0.x = bf16r(a0.x) | (bf16r(a0.y) << 16);
        au0.y = bf16r(a0.z) | (bf16r(a0.w) << 16);
        au0.z = bf16r(a1.x) | (bf16r(a1.y) << 16);
        au0.w = bf16r(a1.z) | (bf16r(a1.w) << 16);
        au1.x = bf16r(b0.x) | (bf16r(b0.y) << 16);
        au1.y = bf16r(b0.z) | (bf16r(b0.w) << 16);
        au1.z = bf16r(b1.x) | (bf16r(b1.y) << 16);
        au1.w = bf16r(b1.z) | (bf16r(b1.w) << 16);
        short8 afrag0 = __builtin_bit_cast(short8, au0);
        short8 afrag1 = __builtin_bit_cast(short8, au1);
        #pragma unroll
        for (int nt = 0; nt < 8; ++nt) {
            const ushort_t* wp = wt + ((nt * 16 + c) * 128 + kk * 32 + g * 8);
            u32x4 bu = *(const u32x4*)wp;               // loaded once...
            short8 bfrag = __builtin_bit_cast(short8, bu);
            acc0[nt] = __builtin_amdgcn_mfma_f32_16x16x32_bf16(afrag0, bfrag, acc0[nt], 0, 0, 0);
            acc1[nt] = __builtin_amdgcn_mfma_f32_16x16x32_bf16(afrag1, bfrag, acc1[nt], 0, 0, 0);  // ...used twice
        }
        {
            const ushort_t* wp2 = wt2 + (c * 128 + kk * 32 + g * 8);
            u32x4 bu2 = *(const u32x4*)wp2;
            short8 bfrag2 = __builtin_bit_cast(short8, bu2);
            acc8v0 = __builtin_amdgcn_mfma_f32_16x16x32_bf16(afrag0, bfrag2, acc8v0, 0, 0, 0);
            acc8v1 = __builtin_amdgcn_mfma_f32_16x16x32_bf16(afrag1, bfrag2, acc8v1, 0, 0, 0);
        }
    }

    #pragma unroll
    for (int r = 0; r < 4; ++r) {
        const int node0 = rowbase + g * 4 + r;
        const int node1 = rowbase + 16 + g * 4 + r;
        if (node0 < N) {
            u32x4 v;
            v.x = bf16r(acc0[0][r]) | (bf16r(acc0[1][r]) << 16);
            v.y = bf16r(acc0[2][r]) | (bf16r(acc0[3][r]) << 16);
            v.z = bf16r(acc0[4][r]) | (bf16r(acc0[5][r]) << 16);
            v.w = bf16r(acc0[6][r]) | (bf16r(acc0[7][r]) << 16);
            *(u32x4*)(feat16 + (size_t)node0 * 128 + c * 8) = v;   // cols 8c..8c+7
            if (c < 4)       el[node0 * 4 + c]       = acc8v0[r];
            else if (c < 8)  er[node0 * 4 + (c - 4)] = acc8v0[r];
        }
        if (node1 < N) {
            u32x4 v;
            v.x = bf16r(acc1[0][r]) | (bf16r(acc1[1][r]) << 16);
            v.y = bf16r(acc1[2][r]) | (bf16r(acc1[3][r]) << 16);
            v.z = bf16r(acc1[4][r]) | (bf16r(acc1[5][r]) << 16);
            v.w = bf16r(acc1[6][r]) | (bf16r(acc1[7][r]) << 16);
            *(u32x4*)(feat16 + (size_t)node1 * 128 + c * 8) = v;
            if (c < 4)       el[node1 * 4 + c]       = acc8v1[r];
            else if (c < 8)  er[node1 * 4 + (c - 4)] = acc8v1[r];
        }
    }
}

// ---------------- k1: wt prep (blocks 0..63) + coarse hist (rest) ---------
__global__ __launch_bounds__(256) void prep_hist_kernel(
    const float* __restrict__ fc_w, const float* __restrict__ attn_l,
    const float* __restrict__ attn_r,
    ushort_t* __restrict__ wt, ushort_t* __restrict__ wt2,
    const int* __restrict__ edst, int* __restrict__ bucketCount, int E, int NB)
{
    __shared__ int hbuf[NB_MAX];

    if (blockIdx.x < 64) {
        int t = blockIdx.x * 256 + threadIdx.x;   // 16384
        int n = t >> 7, k = t & 127;
        // col-permuted: row rho=nt*16+c holds W[:, 8c+nt]
        int colp = 8 * (n & 15) + (n >> 4);
        wt[t] = (ushort_t)bf16r(fc_w[k * 128 + colp]);
        if (t < 2048) {                            // 16 cols x 128 k
            int col = t >> 7;
            int kk  = t & 127;
            float ssum = 0.f;
            if (col < 8) {
                int h = col & 3;
                const float* av = (col < 4) ? attn_l : attn_r;
                #pragma unroll 8
                for (int d = 0; d < 32; ++d)
                    ssum += fc_w[kk * 128 + h * 32 + d] * av[h * 32 + d];
            }
            wt2[col * 128 + kk] = (ushort_t)bf16r(ssum);
        }
        return;
    }

    const int hblk = (int)blockIdx.x - 64;
    for (int t = threadIdx.x; t < NB_MAX; t += 256) hbuf[t] = 0;
    __syncthreads();
    const int base = hblk * EPB;
    #pragma unroll
    for (int rep = 0; rep < EPB / 1024; ++rep) {
        int i = base + (rep * 256 + threadIdx.x) * 4;
        if (i + 3 < E) {
            int4 d = *(const int4*)(edst + i);
            atomicAdd(&hbuf[d.x >> 8], 1);
            atomicAdd(&hbuf[d.y >> 8], 1);
            atomicAdd(&hbuf[d.z >> 8], 1);
            atomicAdd(&hbuf[d.w >> 8], 1);
        } else {
            for (int k = 0; k < 4; ++k)
                if (i + k < E) atomicAdd(&hbuf[edst[i + k] >> 8], 1);
        }
    }
    __syncthreads();
    for (int t = threadIdx.x; t < NB; t += 256)
        if (hbuf[t]) atomicAdd(&bucketCount[t], hbuf[t]);
}

// ---------------- k2: bucket scan -----------------------------------------
__global__ __launch_bounds__(512) void bucket_scan_kernel(
    const int* __restrict__ bucketCount, int* __restrict__ bucketStart,
    int* __restrict__ bucketCursor, int* __restrict__ row_start, int NB, int N)
{
    __shared__ int p[512];
    const int t = threadIdx.x;
    int v = (t < NB) ? bucketCount[t] : 0;
    p[t] = v;
    __syncthreads();
    for (int off = 1; off < 512; off <<= 1) {
        int u = (t >= off) ? p[t - off] : 0;
        __syncthreads();
        p[t] += u;
        __syncthreads();
    }
    if (t < NB) {
        bucketStart[t]  = p[t] - v;
        bucketCursor[t] = p[t] - v;
    }
    if (t == NB - 1) {
        bucketStart[NB] = p[t];
        row_start[N]    = p[t];   // == E
    }
}

// ---------------- k3: bin (blocks < nblkE) + proj part A ------------------
__global__ __launch_bounds__(256) void bin_proj_kernel(
    const int* __restrict__ esrc, const int* __restrict__ edst,
    int* __restrict__ bucketCursor, uint* __restrict__ binned, int E, int NB,
    int nblkE,
    const float* __restrict__ x, const ushort_t* __restrict__ wt,
    const ushort_t* __restrict__ wt2,
    ushort_t* __restrict__ feat16, float* __restrict__ el, float* __restrict__ er,
    int N)
{
    __shared__ int hist[NB_MAX];
    __shared__ int cur[NB_MAX];

    if ((int)blockIdx.x >= nblkE) {
        proj_body((int)blockIdx.x - nblkE, x, wt, wt2, feat16, el, er, N);
        return;
    }

    const int t = threadIdx.x;
    for (int k = t; k < NB_MAX; k += 256) hist[k] = 0;
    __syncthreads();

    const int base = blockIdx.x * EPB;
    #pragma unroll
    for (int rep = 0; rep < EPB / 1024; ++rep) {
        int i = base + (rep * 256 + t) * 4;
        if (i + 3 < E) {
            int4 d = *(const int4*)(edst + i);
            atomicAdd(&hist[d.x >> 8], 1);
            atomicAdd(&hist[d.y >> 8], 1);
            atomicAdd(&hist[d.z >> 8], 1);
            atomicAdd(&hist[d.w >> 8], 1);
        } else {
            for (int k = 0; k < 4; ++k)
                if (i + k < E) atomicAdd(&hist[edst[i + k] >> 8], 1);
        }
    }
    __syncthreads();
    for (int k = t; k < NB; k += 256) {
        int hh = hist[k];
        cur[k] = hh ? atomicAdd(&bucketCursor[k], hh) : 0;
    }
    __syncthreads();
    const int nloc = min(EPB, E - base);
    for (int rep = 0; rep < EPB / 256; ++rep) {
        int idx = rep * 256 + t;
        if (idx < nloc) {
            int dv = edst[base + idx];
            int pos = atomicAdd(&cur[dv >> 8], 1);
            int src = esrc[base + idx];
            binned[pos] = (uint)src | ((uint)(dv & 255) << 24);
        }
    }
}

// ---------------- k4: fine CSR (blocks < NB) + proj part B ----------------
__global__ __launch_bounds__(256) void fine_proj_kernel(
    const uint* __restrict__ binned, const int* __restrict__ bucketStart,
    int* __restrict__ row_start, int* __restrict__ csr, int N, int NBb,
    int projOffset,
    const float* __restrict__ x, const ushort_t* __restrict__ wt,
    const ushort_t* __restrict__ wt2,
    ushort_t* __restrict__ feat16, float* __restrict__ el, float* __restrict__ er)
{
    __shared__ int hist[256], sc[256], cur[256];

    if ((int)blockIdx.x >= NBb) {
        proj_body((int)blockIdx.x - NBb + projOffset, x, wt, wt2, feat16, el, er, N);
        return;
    }

    const int b = blockIdx.x;
    const int t = threadIdx.x;
    const int s = bucketStart[b];
    const int e = bucketStart[b + 1];

    hist[t] = 0;
    __syncthreads();
    for (int i = s + t; i < e; i += 256)
        atomicAdd(&hist[binned[i] >> 24], 1);
    __syncthreads();
    sc[t] = hist[t];
    __syncthreads();
    for (int off = 1; off < 256; off <<= 1) {
        int u = (t >= off) ? sc[t - off] : 0;
        __syncthreads();
        sc[t] += u;
        __syncthreads();
    }
    const int excl = s + sc[t] - hist[t];
    const int gn = b * NPB + t;
    if (gn < N) row_start[gn] = excl;
    cur[t] = excl;
    __syncthreads();
    for (int i = s + t; i < e; i += 256) {
        uint v = binned[i];
        int pos = atomicAdd(&cur[v >> 24], 1);
        csr[pos] = (int)(v & 0xFFFFFFu);
    }
}

// ---------------- aggregation (proven body, byte-identical) ---------------
__global__ __launch_bounds__(256) void aggregate_kernel(
    const u32x4* __restrict__ feat4, const float* __restrict__ el,
    const float* __restrict__ er, const int* __restrict__ row_start,
    const int* __restrict__ csr, const float* __restrict__ bias,
    float* __restrict__ out, int N)
{
    int node = blockIdx.x * 4 + (threadIdx.x >> 6);
    node = __builtin_amdgcn_readfirstlane(node);
    if (node >= N) return;
    const int lane = threadIdx.x & 63;
    const int g  = lane >> 4;        // edge slot 0..3
    const int ll = lane & 15;        // feature octet 0..15
    const int h  = ll >> 2;          // my head

    const int start = row_start[node];
    const int end   = row_start[node + 1];
    const float er_v = er[node * 4 + h];

    float rA0=0.f,rA1=0.f,rA2=0.f,rA3=0.f,rA4=0.f,rA5=0.f,rA6=0.f,rA7=0.f;
    float rB0=0.f,rB1=0.f,rB2=0.f,rB3=0.f,rB4=0.f,rB5=0.f,rB6=0.f,rB7=0.f;
    float sA = 0.f, sB = 0.f;
    const int last = end - 1;

    for (int i0 = start; i0 < end; i0 += 8) {
        const int iA = i0 + g;
        const int iB = i0 + 4 + g;
        const bool vA = iA < end;
        const bool vB = iB < end;
        const int uA = csr[vA ? iA : last];
        const int uB = csr[vB ? iB : last];
        float eA = el[uA * 4 + h];
        float eB = el[uB * 4 + h];
        u32x4 pA = feat4[(size_t)uA * 16 + ll];
        u32x4 pB = feat4[(size_t)uB * 16 + ll];

        eA += er_v; eA = fmaxf(eA, NEG * eA);
        float xA = vA ? __expf(eA) : 0.f;
        eB += er_v; eB = fmaxf(eB, NEG * eB);
        float xB = vB ? __expf(eB) : 0.f;
        sA += xA; sB += xB;

        rA0 = fmaf(xA, __uint_as_float(pA.x << 16),         rA0);
        rA1 = fmaf(xA, __uint_as_float(pA.x & 0xffff0000u), rA1);
        rA2 = fmaf(xA, __uint_as_float(pA.y << 16),         rA2);
        rA3 = fmaf(xA, __uint_as_float(pA.y & 0xffff0000u), rA3);
        rA4 = fmaf(xA, __uint_as_float(pA.z << 16),         rA4);
        rA5 = fmaf(xA, __uint_as_float(pA.z & 0xffff0000u), rA5);
        rA6 = fmaf(xA, __uint_as_float(pA.w << 16),         rA6);
        rA7 = fmaf(xA, __uint_as_float(pA.w & 0xffff0000u), rA7);
        rB0 = fmaf(xB, __uint_as_float(pB.x << 16),         rB0);
        rB1 = fmaf(xB, __uint_as_float(pB.x & 0xffff0000u), rB1);
        rB2 = fmaf(xB, __uint_as_float(pB.y << 16),         rB2);
        rB3 = fmaf(xB, __uint_as_float(pB.y & 0xffff0000u), rB3);
        rB4 = fmaf(xB, __uint_as_float(pB.z << 16),         rB4);
        rB5 = fmaf(xB, __uint_as_float(pB.z & 0xffff0000u), rB5);
        rB6 = fmaf(xB, __uint_as_float(pB.w << 16),         rB6);
        rB7 = fmaf(xB, __uint_as_float(pB.w & 0xffff0000u), rB7);
    }

    float r0 = rA0 + rB0, r1 = rA1 + rB1, r2 = rA2 + rB2, r3 = rA3 + rB3;
    float r4 = rA4 + rB4, r5 = rA5 + rB5, r6 = rA6 + rB6, r7 = rA7 + rB7;
    float s = sA + sB;

    s  += __shfl_xor(s, 16);  s  += __shfl_xor(s, 32);
    r0 += __shfl_xor(r0, 16); r0 += __shfl_xor(r0, 32);
    r1 += __shfl_xor(r1, 16); r1 += __shfl_xor(r1, 32);
    r2 += __shfl_xor(r2, 16); r2 += __shfl_xor(r2, 32);
    r3 += __shfl_xor(r3, 16); r3 += __shfl_xor(r3, 32);
    r4 += __shfl_xor(r4, 16); r4 += __shfl_xor(r4, 32);
    r5 += __shfl_xor(r5, 16); r5 += __shfl_xor(r5, 32);
    r6 += __shfl_xor(r6, 16); r6 += __shfl_xor(r6, 32);
    r7 += __shfl_xor(r7, 16); r7 += __shfl_xor(r7, 32);

    s = fmaxf(s, 1e-16f);
    float inv = 1.0f / s;
    r0 *= inv; r1 *= inv; r2 *= inv; r3 *= inv;
    r4 *= inv; r5 *= inv; r6 *= inv; r7 *= inv;

    r0 += __shfl_xor(r0, 4); r0 += __shfl_xor(r0, 8);
    r1 += __shfl_xor(r1, 4); r1 += __shfl_xor(r1, 8);
    r2 += __shfl_xor(r2, 4); r2 += __shfl_xor(r2, 8);
    r3 += __shfl_xor(r3, 4); r3 += __shfl_xor(r3, 8);
    r4 += __shfl_xor(r4, 4); r4 += __shfl_xor(r4, 8);
    r5 += __shfl_xor(r5, 4); r5 += __shfl_xor(r5, 8);
    r6 += __shfl_xor(r6, 4); r6 += __shfl_xor(r6, 8);
    r7 += __shfl_xor(r7, 4); r7 += __shfl_xor(r7, 8);

    if (lane < 4) {
        const int m0 = lane * 8;
        float4 o0, o1;
        o0.x = 0.25f * (r0 + bias[m0]   + bias[32+m0]   + bias[64+m0]   + bias[96+m0]);
        o0.y = 0.25f * (r1 + bias[m0+1] + bias[33+m0]   + bias[65+m0]   + bias[97+m0]);
        o0.z = 0.25f * (r2 + bias[m0+2] + bias[34+m0]   + bias[66+m0]   + bias[98+m0]);
        o0.w = 0.25f * (r3 + bias[m0+3] + bias[35+m0]   + bias[67+m0]   + bias[99+m0]);
        o1.x = 0.25f * (r4 + bias[m0+4] + bias[36+m0]   + bias[68+m0]   + bias[100+m0]);
        o1.y = 0.25f * (r5 + bias[m0+5] + bias[37+m0]   + bias[69+m0]   + bias[101+m0]);
        o1.z = 0.25f * (r6 + bias[m0+6] + bias[38+m0]   + bias[70+m0]   + bias[102+m0]);
        o1.w = 0.25f * (r7 + bias[m0+7] + bias[39+m0]   + bias[71+m0]   + bias[103+m0]);
        float* op = out + (size_t)node * 32 + m0;
        *(float4*)op       = o0;
        *(float4*)(op + 4) = o1;
    }
}

// ---------------- launch --------------------------------------------------
extern "C" void kernel_launch(void* const* d_in, const int* in_sizes, int n_in,
                              void* d_out, int out_size, void* d_ws, size_t ws_size,
                              hipStream_t stream)
{
    const float* x      = (const float*)d_in[0];
    const int*   esrc   = (const int*)  d_in[1];
    const int*   edst   = (const int*)  d_in[2];
    const float* fc_w   = (const float*)d_in[3];
    const float* attn_l = (const float*)d_in[4];
    const float* attn_r = (const float*)d_in[5];
    const float* bias   = (const float*)d_in[6];
    float* out = (float*)d_out;

    const int N = in_sizes[0] / IN_DIM;   // 100000
    const int E = in_sizes[1];            // 1600000
    const int NB = (N + NPB - 1) / NPB;   // 391

    size_t o = 0;
    char* base = (char*)d_ws;
    auto alloc = [&](size_t bytes) -> void* {
        void* p = base + o;
        o += (bytes + 255) & ~(size_t)255;
        return p;
    };
    ushort_t* feat16   = (ushort_t*)alloc((size_t)N * 128 * sizeof(ushort_t));
    float* el          = (float*)alloc((size_t)N * 4 * sizeof(float));
    float* er          = (float*)alloc((size_t)N * 4 * sizeof(float));
    int*   row_start   = (int*)  alloc(((size_t)N + 1) * sizeof(int));
    int*   csr         = (int*)  alloc((size_t)E * sizeof(int));
    uint*  binned      = (uint*) alloc((size_t)E * sizeof(uint));
    int*   bucketCount = (int*)  alloc(NB_MAX * sizeof(int));
    int*   bucketStart = (int*)  alloc((NB_MAX + 1) * sizeof(int));
    int*   bucketCursor= (int*)  alloc(NB_MAX * sizeof(int));
    ushort_t* wt       = (ushort_t*)alloc((size_t)128 * 128 * sizeof(ushort_t));
    ushort_t* wt2      = (ushort_t*)alloc((size_t)16 * 128 * sizeof(ushort_t));
    (void)ws_size;

    const int nblkE = (E + EPB - 1) / EPB;    // 196
    const int nblkP = (N + 127) / 128;        // 782 (proj blocks = 128 rows)
    const int projA = nblkP / 2;              // 391 in k3
    const int projB = nblkP - projA;          // 391 in k4

    hipMemsetAsync(bucketCount, 0, NB_MAX * sizeof(int), stream);

    prep_hist_kernel<<<64 + nblkE, 256, 0, stream>>>(
        fc_w, attn_l, attn_r, wt, wt2, edst, bucketCount, E, NB);
    bucket_scan_kernel<<<1, 512, 0, stream>>>(bucketCount, bucketStart,
                                              bucketCursor, row_start, NB, N);
    bin_proj_kernel<<<nblkE + projA, 256, 0, stream>>>(
        esrc, edst, bucketCursor, binned, E, NB, nblkE,
        x, wt, wt2, feat16, el, er, N);
    fine_proj_kernel<<<NB + projB, 256, 0, stream>>>(
        binned, bucketStart, row_start, csr, N, NB, projA,
        x, wt, wt2, feat16, el, er);
    aggregate_kernel<<<(N + 3) / 4, 256, 0, stream>>>((const u32x4*)feat16, el, er,
                                                      row_start, csr, bias, out, N);
}

// Round 15
// 145.221 us; speedup vs baseline: 1.0386x; 1.0386x over previous
//
#include <hip/hip_runtime.h>

#define IN_DIM 128
#define HEADS 4
#define OUT_DIM 32
#define NEG 0.2f

#define NPB 256        // nodes per bucket (bucket = dst >> 8)
#define NB_MAX 400     // max buckets (N=100000 -> 391)
#define EPB 8192       // edges per block in hist/bin kernels

#define WROW 136       // LDS row stride in ushorts (272B: 16B-aligned, conflict-free)

typedef unsigned int uint;
typedef unsigned short ushort_t;
typedef short short8 __attribute__((ext_vector_type(8)));
typedef float f32x4 __attribute__((ext_vector_type(4)));
typedef uint u32x4 __attribute__((ext_vector_type(4)));

__device__ __forceinline__ uint bf16r(float f) {
    uint u = __float_as_uint(f);
    return (u + 0x7fffu + ((u >> 16) & 1u)) >> 16;   // RNE
}

// ---------------- proj body: 32 rows/wave, LDS-staged wt ------------------
// B-loads were L2-latency bound (r13 B-reuse -11.5us; r11/r14 VALU/store
// fixes neutral). Stage wt(128 rows)+wt2(16 rows) into LDS once per block;
// inner loop B-frags become ds_read_b128 (~12cy vs ~200cy L2).
// lds_w layout: row r at r*WROW ushorts; rows 0..127 = wt, 128..143 = wt2.
__device__ __forceinline__ void proj_body(
    int pblk, const float* __restrict__ x, const ushort_t* __restrict__ wt,
    const ushort_t* __restrict__ wt2, ushort_t* __restrict__ lds_w,
    ushort_t* __restrict__ feat16, float* __restrict__ el, float* __restrict__ er,
    int N)
{
    // ---- stage weights: 2304 dwordx4 chunks, 9 per thread ----
    for (int q = threadIdx.x; q < 2304; q += 256) {
        const int row = q >> 4;           // 0..143
        const int ch  = q & 15;           // 16B chunk within row
        const ushort_t* src = (row < 128) ? (wt + row * 128 + ch * 8)
                                          : (wt2 + (row - 128) * 128 + ch * 8);
        *(u32x4*)(lds_w + row * WROW + ch * 8) = *(const u32x4*)src;
    }
    __syncthreads();

    const int lane = threadIdx.x & 63;
    const int w    = threadIdx.x >> 6;
    const int rowbase = pblk * 128 + w * 32;   // 32 rows per wave
    const int c = lane & 15;
    const int g = lane >> 4;

    f32x4 acc0[8], acc1[8];
    #pragma unroll
    for (int nt = 0; nt < 8; ++nt) {
        acc0[nt] = (f32x4){0.f, 0.f, 0.f, 0.f};
        acc1[nt] = (f32x4){0.f, 0.f, 0.f, 0.f};
    }
    f32x4 acc8v0 = (f32x4){0.f, 0.f, 0.f, 0.f};
    f32x4 acc8v1 = (f32x4){0.f, 0.f, 0.f, 0.f};

    const int arow0 = rowbase + c;
    const int arow1 = rowbase + 16 + c;
    const int arow0c = (arow0 < N) ? arow0 : (N - 1);
    const int arow1c = (arow1 < N) ? arow1 : (N - 1);
    const float* xrow0 = x + (size_t)arow0c * 128 + g * 8;
    const float* xrow1 = x + (size_t)arow1c * 128 + g * 8;

    #pragma unroll
    for (int kk = 0; kk < 4; ++kk) {
        float4 a0 = *(const float4*)(xrow0 + kk * 32);
        float4 a1 = *(const float4*)(xrow0 + kk * 32 + 4);
        float4 b0 = *(const float4*)(xrow1 + kk * 32);
        float4 b1 = *(const float4*)(xrow1 + kk * 32 + 4);
        u32x4 au0, au1;
        au0.x = bf16r(a0.x) | (bf16r(a0.y) << 16);
        au0.y = bf16r(a0.z) | (bf16r(a0.w) << 16);
        au0.z = bf16r(a1.x) | (bf16r(a1.y) << 16);
        au0.w = bf16r(a1.z) | (bf16r(a1.w) << 16);
        au1.x = bf16r(b0.x) | (bf16r(b0.y) << 16);
        au1.y = bf16r(b0.z) | (bf16r(b0.w) << 16);
        au1.z = bf16r(b1.x) | (bf16r(b1.y) << 16);
        au1.w = bf16r(b1.z) | (bf16r(b1.w) << 16);
        short8 afrag0 = __builtin_bit_cast(short8, au0);
        short8 afrag1 = __builtin_bit_cast(short8, au1);
        #pragma unroll
        for (int nt = 0; nt < 8; ++nt) {
            const ushort_t* wp = lds_w + (nt * 16 + c) * WROW + kk * 32 + g * 8;
            u32x4 bu = *(const u32x4*)wp;               // ds_read_b128, conflict-free
            short8 bfrag = __builtin_bit_cast(short8, bu);
            acc0[nt] = __builtin_amdgcn_mfma_f32_16x16x32_bf16(afrag0, bfrag, acc0[nt], 0, 0, 0);
            acc1[nt] = __builtin_amdgcn_mfma_f32_16x16x32_bf16(afrag1, bfrag, acc1[nt], 0, 0, 0);
        }
        {
            const ushort_t* wp2 = lds_w + (128 + c) * WROW + kk * 32 + g * 8;
            u32x4 bu2 = *(const u32x4*)wp2;
            short8 bfrag2 = __builtin_bit_cast(short8, bu2);
            acc8v0 = __builtin_amdgcn_mfma_f32_16x16x32_bf16(afrag0, bfrag2, acc8v0, 0, 0, 0);
            acc8v1 = __builtin_amdgcn_mfma_f32_16x16x32_bf16(afrag1, bfrag2, acc8v1, 0, 0, 0);
        }
    }

    #pragma unroll
    for (int r = 0; r < 4; ++r) {
        const int node0 = rowbase + g * 4 + r;
        const int node1 = rowbase + 16 + g * 4 + r;
        if (node0 < N) {
            u32x4 v;
            v.x = bf16r(acc0[0][r]) | (bf16r(acc0[1][r]) << 16);
            v.y = bf16r(acc0[2][r]) | (bf16r(acc0[3][r]) << 16);
            v.z = bf16r(acc0[4][r]) | (bf16r(acc0[5][r]) << 16);
            v.w = bf16r(acc0[6][r]) | (bf16r(acc0[7][r]) << 16);
            *(u32x4*)(feat16 + (size_t)node0 * 128 + c * 8) = v;
            if (c < 4)       el[node0 * 4 + c]       = acc8v0[r];
            else if (c < 8)  er[node0 * 4 + (c - 4)] = acc8v0[r];
        }
        if (node1 < N) {
            u32x4 v;
            v.x = bf16r(acc1[0][r]) | (bf16r(acc1[1][r]) << 16);
            v.y = bf16r(acc1[2][r]) | (bf16r(acc1[3][r]) << 16);
            v.z = bf16r(acc1[4][r]) | (bf16r(acc1[5][r]) << 16);
            v.w = bf16r(acc1[6][r]) | (bf16r(acc1[7][r]) << 16);
            *(u32x4*)(feat16 + (size_t)node1 * 128 + c * 8) = v;
            if (c < 4)       el[node1 * 4 + c]       = acc8v1[r];
            else if (c < 8)  er[node1 * 4 + (c - 4)] = acc8v1[r];
        }
    }
}

// ---------------- k1: wt prep (blocks 0..63) + coarse hist (rest) ---------
__global__ __launch_bounds__(256) void prep_hist_kernel(
    const float* __restrict__ fc_w, const float* __restrict__ attn_l,
    const float* __restrict__ attn_r,
    ushort_t* __restrict__ wt, ushort_t* __restrict__ wt2,
    const int* __restrict__ edst, int* __restrict__ bucketCount, int E, int NB)
{
    __shared__ int hbuf[NB_MAX];

    if (blockIdx.x < 64) {
        int t = blockIdx.x * 256 + threadIdx.x;   // 16384
        int n = t >> 7, k = t & 127;
        // col-permuted: row rho=nt*16+c holds W[:, 8c+nt]
        int colp = 8 * (n & 15) + (n >> 4);
        wt[t] = (ushort_t)bf16r(fc_w[k * 128 + colp]);
        if (t < 2048) {                            // 16 cols x 128 k
            int col = t >> 7;
            int kk  = t & 127;
            float ssum = 0.f;
            if (col < 8) {
                int h = col & 3;
                const float* av = (col < 4) ? attn_l : attn_r;
                #pragma unroll 8
                for (int d = 0; d < 32; ++d)
                    ssum += fc_w[kk * 128 + h * 32 + d] * av[h * 32 + d];
            }
            wt2[col * 128 + kk] = (ushort_t)bf16r(ssum);
        }
        return;
    }

    const int hblk = (int)blockIdx.x - 64;
    for (int t = threadIdx.x; t < NB_MAX; t += 256) hbuf[t] = 0;
    __syncthreads();
    const int base = hblk * EPB;
    #pragma unroll
    for (int rep = 0; rep < EPB / 1024; ++rep) {
        int i = base + (rep * 256 + threadIdx.x) * 4;
        if (i + 3 < E) {
            int4 d = *(const int4*)(edst + i);
            atomicAdd(&hbuf[d.x >> 8], 1);
            atomicAdd(&hbuf[d.y >> 8], 1);
            atomicAdd(&hbuf[d.z >> 8], 1);
            atomicAdd(&hbuf[d.w >> 8], 1);
        } else {
            for (int k = 0; k < 4; ++k)
                if (i + k < E) atomicAdd(&hbuf[edst[i + k] >> 8], 1);
        }
    }
    __syncthreads();
    for (int t = threadIdx.x; t < NB; t += 256)
        if (hbuf[t]) atomicAdd(&bucketCount[t], hbuf[t]);
}

// ---------------- k2: bucket scan -----------------------------------------
__global__ __launch_bounds__(512) void bucket_scan_kernel(
    const int* __restrict__ bucketCount, int* __restrict__ bucketStart,
    int* __restrict__ bucketCursor, int* __restrict__ row_start, int NB, int N)
{
    __shared__ int p[512];
    const int t = threadIdx.x;
    int v = (t < NB) ? bucketCount[t] : 0;
    p[t] = v;
    __syncthreads();
    for (int off = 1; off < 512; off <<= 1) {
        int u = (t >= off) ? p[t - off] : 0;
        __syncthreads();
        p[t] += u;
        __syncthreads();
    }
    if (t < NB) {
        bucketStart[t]  = p[t] - v;
        bucketCursor[t] = p[t] - v;
    }
    if (t == NB - 1) {
        bucketStart[NB] = p[t];
        row_start[N]    = p[t];   // == E
    }
}

// ---------------- k3: bin (blocks < nblkE) + proj part A ------------------
__global__ __launch_bounds__(256) void bin_proj_kernel(
    const int* __restrict__ esrc, const int* __restrict__ edst,
    int* __restrict__ bucketCursor, uint* __restrict__ binned, int E, int NB,
    int nblkE,
    const float* __restrict__ x, const ushort_t* __restrict__ wt,
    const ushort_t* __restrict__ wt2,
    ushort_t* __restrict__ feat16, float* __restrict__ el, float* __restrict__ er,
    int N)
{
    __shared__ ushort_t lds_w[144 * WROW];   // 38.25 KB (covers hist/cur too)

    if ((int)blockIdx.x >= nblkE) {
        proj_body((int)blockIdx.x - nblkE, x, wt, wt2, lds_w, feat16, el, er, N);
        return;
    }

    int* hist = (int*)lds_w;           // reuse LDS: NB_MAX ints
    int* cur  = (int*)lds_w + NB_MAX;

    const int t = threadIdx.x;
    for (int k = t; k < NB_MAX; k += 256) hist[k] = 0;
    __syncthreads();

    const int base = blockIdx.x * EPB;
    #pragma unroll
    for (int rep = 0; rep < EPB / 1024; ++rep) {
        int i = base + (rep * 256 + t) * 4;
        if (i + 3 < E) {
            int4 d = *(const int4*)(edst + i);
            atomicAdd(&hist[d.x >> 8], 1);
            atomicAdd(&hist[d.y >> 8], 1);
            atomicAdd(&hist[d.z >> 8], 1);
            atomicAdd(&hist[d.w >> 8], 1);
        } else {
            for (int k = 0; k < 4; ++k)
                if (i + k < E) atomicAdd(&hist[edst[i + k] >> 8], 1);
        }
    }
    __syncthreads();
    for (int k = t; k < NB; k += 256) {
        int hh = hist[k];
        cur[k] = hh ? atomicAdd(&bucketCursor[k], hh) : 0;
    }
    __syncthreads();
    const int nloc = min(EPB, E - base);
    for (int rep = 0; rep < EPB / 256; ++rep) {
        int idx = rep * 256 + t;
        if (idx < nloc) {
            int dv = edst[base + idx];
            int pos = atomicAdd(&cur[dv >> 8], 1);
            int src = esrc[base + idx];
            binned[pos] = (uint)src | ((uint)(dv & 255) << 24);
        }
    }
}

// ---------------- k4: fine CSR (blocks < NB) + proj part B ----------------
__global__ __launch_bounds__(256) void fine_proj_kernel(
    const uint* __restrict__ binned, const int* __restrict__ bucketStart,
    int* __restrict__ row_start, int* __restrict__ csr, int N, int NBb,
    int projOffset,
    const float* __restrict__ x, const ushort_t* __restrict__ wt,
    const ushort_t* __restrict__ wt2,
    ushort_t* __restrict__ feat16, float* __restrict__ el, float* __restrict__ er)
{
    __shared__ ushort_t lds_w[144 * WROW];

    if ((int)blockIdx.x >= NBb) {
        proj_body((int)blockIdx.x - NBb + projOffset, x, wt, wt2, lds_w, feat16, el, er, N);
        return;
    }

    int* hist = (int*)lds_w;          // 256 ints
    int* sc   = (int*)lds_w + 256;
    int* cur  = (int*)lds_w + 512;

    const int b = blockIdx.x;
    const int t = threadIdx.x;
    const int s = bucketStart[b];
    const int e = bucketStart[b + 1];

    hist[t] = 0;
    __syncthreads();
    for (int i = s + t; i < e; i += 256)
        atomicAdd(&hist[binned[i] >> 24], 1);
    __syncthreads();
    sc[t] = hist[t];
    __syncthreads();
    for (int off = 1; off < 256; off <<= 1) {
        int u = (t >= off) ? sc[t - off] : 0;
        __syncthreads();
        sc[t] += u;
        __syncthreads();
    }
    const int excl = s + sc[t] - hist[t];
    const int gn = b * NPB + t;
    if (gn < N) row_start[gn] = excl;
    cur[t] = excl;
    __syncthreads();
    for (int i = s + t; i < e; i += 256) {
        uint v = binned[i];
        int pos = atomicAdd(&cur[v >> 24], 1);
        csr[pos] = (int)(v & 0xFFFFFFu);
    }
}

// ---------------- aggregation (proven body, byte-identical) ---------------
__global__ __launch_bounds__(256) void aggregate_kernel(
    const u32x4* __restrict__ feat4, const float* __restrict__ el,
    const float* __restrict__ er, const int* __restrict__ row_start,
    const int* __restrict__ csr, const float* __restrict__ bias,
    float* __restrict__ out, int N)
{
    int node = blockIdx.x * 4 + (threadIdx.x >> 6);
    node = __builtin_amdgcn_readfirstlane(node);
    if (node >= N) return;
    const int lane = threadIdx.x & 63;
    const int g  = lane >> 4;        // edge slot 0..3
    const int ll = lane & 15;        // feature octet 0..15
    const int h  = ll >> 2;          // my head

    const int start = row_start[node];
    const int end   = row_start[node + 1];
    const float er_v = er[node * 4 + h];

    float rA0=0.f,rA1=0.f,rA2=0.f,rA3=0.f,rA4=0.f,rA5=0.f,rA6=0.f,rA7=0.f;
    float rB0=0.f,rB1=0.f,rB2=0.f,rB3=0.f,rB4=0.f,rB5=0.f,rB6=0.f,rB7=0.f;
    float sA = 0.f, sB = 0.f;
    const int last = end - 1;

    for (int i0 = start; i0 < end; i0 += 8) {
        const int iA = i0 + g;
        const int iB = i0 + 4 + g;
        const bool vA = iA < end;
        const bool vB = iB < end;
        const int uA = csr[vA ? iA : last];
        const int uB = csr[vB ? iB : last];
        float eA = el[uA * 4 + h];
        float eB = el[uB * 4 + h];
        u32x4 pA = feat4[(size_t)uA * 16 + ll];
        u32x4 pB = feat4[(size_t)uB * 16 + ll];

        eA += er_v; eA = fmaxf(eA, NEG * eA);
        float xA = vA ? __expf(eA) : 0.f;
        eB += er_v; eB = fmaxf(eB, NEG * eB);
        float xB = vB ? __expf(eB) : 0.f;
        sA += xA; sB += xB;

        rA0 = fmaf(xA, __uint_as_float(pA.x << 16),         rA0);
        rA1 = fmaf(xA, __uint_as_float(pA.x & 0xffff0000u), rA1);
        rA2 = fmaf(xA, __uint_as_float(pA.y << 16),         rA2);
        rA3 = fmaf(xA, __uint_as_float(pA.y & 0xffff0000u), rA3);
        rA4 = fmaf(xA, __uint_as_float(pA.z << 16),         rA4);
        rA5 = fmaf(xA, __uint_as_float(pA.z & 0xffff0000u), rA5);
        rA6 = fmaf(xA, __uint_as_float(pA.w << 16),         rA6);
        rA7 = fmaf(xA, __uint_as_float(pA.w & 0xffff0000u), rA7);
        rB0 = fmaf(xB, __uint_as_float(pB.x << 16),         rB0);
        rB1 = fmaf(xB, __uint_as_float(pB.x & 0xffff0000u), rB1);
        rB2 = fmaf(xB, __uint_as_float(pB.y << 16),         rB2);
        rB3 = fmaf(xB, __uint_as_float(pB.y & 0xffff0000u), rB3);
        rB4 = fmaf(xB, __uint_as_float(pB.z << 16),         rB4);
        rB5 = fmaf(xB, __uint_as_float(pB.z & 0xffff0000u), rB5);
        rB6 = fmaf(xB, __uint_as_float(pB.w << 16),         rB6);
        rB7 = fmaf(xB, __uint_as_float(pB.w & 0xffff0000u), rB7);
    }

    float r0 = rA0 + rB0, r1 = rA1 + rB1, r2 = rA2 + rB2, r3 = rA3 + rB3;
    float r4 = rA4 + rB4, r5 = rA5 + rB5, r6 = rA6 + rB6, r7 = rA7 + rB7;
    float s = sA + sB;

    s  += __shfl_xor(s, 16);  s  += __shfl_xor(s, 32);
    r0 += __shfl_xor(r0, 16); r0 += __shfl_xor(r0, 32);
    r1 += __shfl_xor(r1, 16); r1 += __shfl_xor(r1, 32);
    r2 += __shfl_xor(r2, 16); r2 += __shfl_xor(r2, 32);
    r3 += __shfl_xor(r3, 16); r3 += __shfl_xor(r3, 32);
    r4 += __shfl_xor(r4, 16); r4 += __shfl_xor(r4, 32);
    r5 += __shfl_xor(r5, 16); r5 += __shfl_xor(r5, 32);
    r6 += __shfl_xor(r6, 16); r6 += __shfl_xor(r6, 32);
    r7 += __shfl_xor(r7, 16); r7 += __shfl_xor(r7, 32);

    s = fmaxf(s, 1e-16f);
    float inv = 1.0f / s;
    r0 *= inv; r1 *= inv; r2 *= inv; r3 *= inv;
    r4 *= inv; r5 *= inv; r6 *= inv; r7 *= inv;

    r0 += __shfl_xor(r0, 4); r0 += __shfl_xor(r0, 8);
    r1 += __shfl_xor(r1, 4); r1 += __shfl_xor(r1, 8);
    r2 += __shfl_xor(r2, 4); r2 += __shfl_xor(r2, 8);
    r3 += __shfl_xor(r3, 4); r3 += __shfl_xor(r3, 8);
    r4 += __shfl_xor(r4, 4); r4 += __shfl_xor(r4, 8);
    r5 += __shfl_xor(r5, 4); r5 += __shfl_xor(r5, 8);
    r6 += __shfl_xor(r6, 4); r6 += __shfl_xor(r6, 8);
    r7 += __shfl_xor(r7, 4); r7 += __shfl_xor(r7, 8);

    if (lane < 4) {
        const int m0 = lane * 8;
        float4 o0, o1;
        o0.x = 0.25f * (r0 + bias[m0]   + bias[32+m0]   + bias[64+m0]   + bias[96+m0]);
        o0.y = 0.25f * (r1 + bias[m0+1] + bias[33+m0]   + bias[65+m0]   + bias[97+m0]);
        o0.z = 0.25f * (r2 + bias[m0+2] + bias[34+m0]   + bias[66+m0]   + bias[98+m0]);
        o0.w = 0.25f * (r3 + bias[m0+3] + bias[35+m0]   + bias[67+m0]   + bias[99+m0]);
        o1.x = 0.25f * (r4 + bias[m0+4] + bias[36+m0]   + bias[68+m0]   + bias[100+m0]);
        o1.y = 0.25f * (r5 + bias[m0+5] + bias[37+m0]   + bias[69+m0]   + bias[101+m0]);
        o1.z = 0.25f * (r6 + bias[m0+6] + bias[38+m0]   + bias[70+m0]   + bias[102+m0]);
        o1.w = 0.25f * (r7 + bias[m0+7] + bias[39+m0]   + bias[71+m0]   + bias[103+m0]);
        float* op = out + (size_t)node * 32 + m0;
        *(float4*)op       = o0;
        *(float4*)(op + 4) = o1;
    }
}

// ---------------- launch --------------------------------------------------
extern "C" void kernel_launch(void* const* d_in, const int* in_sizes, int n_in,
                              void* d_out, int out_size, void* d_ws, size_t ws_size,
                              hipStream_t stream)
{
    const float* x      = (const float*)d_in[0];
    const int*   esrc   = (const int*)  d_in[1];
    const int*   edst   = (const int*)  d_in[2];
    const float* fc_w   = (const float*)d_in[3];
    const float* attn_l = (const float*)d_in[4];
    const float* attn_r = (const float*)d_in[5];
    const float* bias   = (const float*)d_in[6];
    float* out = (float*)d_out;

    const int N = in_sizes[0] / IN_DIM;   // 100000
    const int E = in_sizes[1];            // 1600000
    const int NB = (N + NPB - 1) / NPB;   // 391

    size_t o = 0;
    char* base = (char*)d_ws;
    auto alloc = [&](size_t bytes) -> void* {
        void* p = base + o;
        o += (bytes + 255) & ~(size_t)255;
        return p;
    };
    ushort_t* feat16   = (ushort_t*)alloc((size_t)N * 128 * sizeof(ushort_t));
    float* el          = (float*)alloc((size_t)N * 4 * sizeof(float));
    float* er          = (float*)alloc((size_t)N * 4 * sizeof(float));
    int*   row_start   = (int*)  alloc(((size_t)N + 1) * sizeof(int));
    int*   csr         = (int*)  alloc((size_t)E * sizeof(int));
    uint*  binned      = (uint*) alloc((size_t)E * sizeof(uint));
    int*   bucketCount = (int*)  alloc(NB_MAX * sizeof(int));
    int*   bucketStart = (int*)  alloc((NB_MAX + 1) * sizeof(int));
    int*   bucketCursor= (int*)  alloc(NB_MAX * sizeof(int));
    ushort_t* wt       = (ushort_t*)alloc((size_t)128 * 128 * sizeof(ushort_t));
    ushort_t* wt2      = (ushort_t*)alloc((size_t)16 * 128 * sizeof(ushort_t));
    (void)ws_size;

    const int nblkE = (E + EPB - 1) / EPB;    // 196
    const int nblkP = (N + 127) / 128;        // 782 (proj blocks = 128 rows)
    const int projA = nblkP / 2;              // 391 in k3
    const int projB = nblkP - projA;          // 391 in k4

    hipMemsetAsync(bucketCount, 0, NB_MAX * sizeof(int), stream);

    prep_hist_kernel<<<64 + nblkE, 256, 0, stream>>>(
        fc_w, attn_l, attn_r, wt, wt2, edst, bucketCount, E, NB);
    bucket_scan_kernel<<<1, 512, 0, stream>>>(bucketCount, bucketStart,
                                              bucketCursor, row_start, NB, N);
    bin_proj_kernel<<<nblkE + projA, 256, 0, stream>>>(
        esrc, edst, bucketCursor, binned, E, NB, nblkE,
        x, wt, wt2, feat16, el, er, N);
    fine_proj_kernel<<<NB + projB, 256, 0, stream>>>(
        binned, bucketStart, row_start, csr, N, NB, projA,
        x, wt, wt2, feat16, el, er);
    aggregate_kernel<<<(N + 3) / 4, 256, 0, stream>>>((const u32x4*)feat16, el, er,
                                                      row_start, csr, bias, out, N);
}

// Round 16
// 144.108 us; speedup vs baseline: 1.0466x; 1.0077x over previous
//
#include <hip/hip_runtime.h>

#define IN_DIM 128
#define HEADS 4
#define OUT_DIM 32
#define NEG 0.2f

#define NPB 256        // nodes per bucket (bucket = dst >> 8)
#define NB_MAX 400     // max buckets (N=100000 -> 391)
#define EPB 8192       // edges per block in hist/bin kernels

#define WROW 136       // LDS row stride in ushorts (272B: 16B-aligned, conflict-free)

typedef unsigned int uint;
typedef unsigned short ushort_t;
typedef short short8 __attribute__((ext_vector_type(8)));
typedef float f32x4 __attribute__((ext_vector_type(4)));
typedef uint u32x4 __attribute__((ext_vector_type(4)));

__device__ __forceinline__ uint bf16r(float f) {
    uint u = __float_as_uint(f);
    return (u + 0x7fffu + ((u >> 16) & 1u)) >> 16;   // RNE
}

// ---------------- proj body: 32 rows/wave, LDS-staged wt (r15 verbatim) ---
__device__ __forceinline__ void proj_body(
    int pblk, const float* __restrict__ x, const ushort_t* __restrict__ wt,
    const ushort_t* __restrict__ wt2, ushort_t* __restrict__ lds_w,
    ushort_t* __restrict__ feat16, float* __restrict__ el, float* __restrict__ er,
    int N)
{
    // ---- stage weights: 2304 dwordx4 chunks, 9 per thread ----
    for (int q = threadIdx.x; q < 2304; q += 256) {
        const int row = q >> 4;           // 0..143
        const int ch  = q & 15;           // 16B chunk within row
        const ushort_t* src = (row < 128) ? (wt + row * 128 + ch * 8)
                                          : (wt2 + (row - 128) * 128 + ch * 8);
        *(u32x4*)(lds_w + row * WROW + ch * 8) = *(const u32x4*)src;
    }
    __syncthreads();

    const int lane = threadIdx.x & 63;
    const int w    = threadIdx.x >> 6;
    const int rowbase = pblk * 128 + w * 32;   // 32 rows per wave
    const int c = lane & 15;
    const int g = lane >> 4;

    f32x4 acc0[8], acc1[8];
    #pragma unroll
    for (int nt = 0; nt < 8; ++nt) {
        acc0[nt] = (f32x4){0.f, 0.f, 0.f, 0.f};
        acc1[nt] = (f32x4){0.f, 0.f, 0.f, 0.f};
    }
    f32x4 acc8v0 = (f32x4){0.f, 0.f, 0.f, 0.f};
    f32x4 acc8v1 = (f32x4){0.f, 0.f, 0.f, 0.f};

    const int arow0 = rowbase + c;
    const int arow1 = rowbase + 16 + c;
    const int arow0c = (arow0 < N) ? arow0 : (N - 1);
    const int arow1c = (arow1 < N) ? arow1 : (N - 1);
    const float* xrow0 = x + (size_t)arow0c * 128 + g * 8;
    const float* xrow1 = x + (size_t)arow1c * 128 + g * 8;

    #pragma unroll
    for (int kk = 0; kk < 4; ++kk) {
        float4 a0 = *(const float4*)(xrow0 + kk * 32);
        float4 a1 = *(const float4*)(xrow0 + kk * 32 + 4);
        float4 b0 = *(const float4*)(xrow1 + kk * 32);
        float4 b1 = *(const float4*)(xrow1 + kk * 32 + 4);
        u32x4 au0, au1;
        au0.x = bf16r(a0.x) | (bf16r(a0.y) << 16);
        au0.y = bf16r(a0.z) | (bf16r(a0.w) << 16);
        au0.z = bf16r(a1.x) | (bf16r(a1.y) << 16);
        au0.w = bf16r(a1.z) | (bf16r(a1.w) << 16);
        au1.x = bf16r(b0.x) | (bf16r(b0.y) << 16);
        au1.y = bf16r(b0.z) | (bf16r(b0.w) << 16);
        au1.z = bf16r(b1.x) | (bf16r(b1.y) << 16);
        au1.w = bf16r(b1.z) | (bf16r(b1.w) << 16);
        short8 afrag0 = __builtin_bit_cast(short8, au0);
        short8 afrag1 = __builtin_bit_cast(short8, au1);
        #pragma unroll
        for (int nt = 0; nt < 8; ++nt) {
            const ushort_t* wp = lds_w + (nt * 16 + c) * WROW + kk * 32 + g * 8;
            u32x4 bu = *(const u32x4*)wp;               // ds_read_b128, conflict-free
            short8 bfrag = __builtin_bit_cast(short8, bu);
            acc0[nt] = __builtin_amdgcn_mfma_f32_16x16x32_bf16(afrag0, bfrag, acc0[nt], 0, 0, 0);
            acc1[nt] = __builtin_amdgcn_mfma_f32_16x16x32_bf16(afrag1, bfrag, acc1[nt], 0, 0, 0);
        }
        {
            const ushort_t* wp2 = lds_w + (128 + c) * WROW + kk * 32 + g * 8;
            u32x4 bu2 = *(const u32x4*)wp2;
            short8 bfrag2 = __builtin_bit_cast(short8, bu2);
            acc8v0 = __builtin_amdgcn_mfma_f32_16x16x32_bf16(afrag0, bfrag2, acc8v0, 0, 0, 0);
            acc8v1 = __builtin_amdgcn_mfma_f32_16x16x32_bf16(afrag1, bfrag2, acc8v1, 0, 0, 0);
        }
    }

    #pragma unroll
    for (int r = 0; r < 4; ++r) {
        const int node0 = rowbase + g * 4 + r;
        const int node1 = rowbase + 16 + g * 4 + r;
        if (node0 < N) {
            u32x4 v;
            v.x = bf16r(acc0[0][r]) | (bf16r(acc0[1][r]) << 16);
            v.y = bf16r(acc0[2][r]) | (bf16r(acc0[3][r]) << 16);
            v.z = bf16r(acc0[4][r]) | (bf16r(acc0[5][r]) << 16);
            v.w = bf16r(acc0[6][r]) | (bf16r(acc0[7][r]) << 16);
            *(u32x4*)(feat16 + (size_t)node0 * 128 + c * 8) = v;
            if (c < 4)       el[node0 * 4 + c]       = acc8v0[r];
            else if (c < 8)  er[node0 * 4 + (c - 4)] = acc8v0[r];
        }
        if (node1 < N) {
            u32x4 v;
            v.x = bf16r(acc1[0][r]) | (bf16r(acc1[1][r]) << 16);
            v.y = bf16r(acc1[2][r]) | (bf16r(acc1[3][r]) << 16);
            v.z = bf16r(acc1[4][r]) | (bf16r(acc1[5][r]) << 16);
            v.w = bf16r(acc1[6][r]) | (bf16r(acc1[7][r]) << 16);
            *(u32x4*)(feat16 + (size_t)node1 * 128 + c * 8) = v;
            if (c < 4)       el[node1 * 4 + c]       = acc8v1[r];
            else if (c < 8)  er[node1 * 4 + (c - 4)] = acc8v1[r];
        }
    }
}

// ---------------- k1: wt prep (blocks 0..63) + coarse hist (rest) ---------
__global__ __launch_bounds__(256) void prep_hist_kernel(
    const float* __restrict__ fc_w, const float* __restrict__ attn_l,
    const float* __restrict__ attn_r,
    ushort_t* __restrict__ wt, ushort_t* __restrict__ wt2,
    const int* __restrict__ edst, int* __restrict__ bucketCount, int E, int NB)
{
    __shared__ int hbuf[NB_MAX];

    if (blockIdx.x < 64) {
        int t = blockIdx.x * 256 + threadIdx.x;   // 16384
        int n = t >> 7, k = t & 127;
        // col-permuted: row rho=nt*16+c holds W[:, 8c+nt]
        int colp = 8 * (n & 15) + (n >> 4);
        wt[t] = (ushort_t)bf16r(fc_w[k * 128 + colp]);
        if (t < 2048) {                            // 16 cols x 128 k
            int col = t >> 7;
            int kk  = t & 127;
            float ssum = 0.f;
            if (col < 8) {
                int h = col & 3;
                const float* av = (col < 4) ? attn_l : attn_r;
                #pragma unroll 8
                for (int d = 0; d < 32; ++d)
                    ssum += fc_w[kk * 128 + h * 32 + d] * av[h * 32 + d];
            }
            wt2[col * 128 + kk] = (ushort_t)bf16r(ssum);
        }
        return;
    }

    const int hblk = (int)blockIdx.x - 64;
    for (int t = threadIdx.x; t < NB_MAX; t += 256) hbuf[t] = 0;
    __syncthreads();
    const int base = hblk * EPB;
    #pragma unroll
    for (int rep = 0; rep < EPB / 1024; ++rep) {
        int i = base + (rep * 256 + threadIdx.x) * 4;
        if (i + 3 < E) {
            int4 d = *(const int4*)(edst + i);
            atomicAdd(&hbuf[d.x >> 8], 1);
            atomicAdd(&hbuf[d.y >> 8], 1);
            atomicAdd(&hbuf[d.z >> 8], 1);
            atomicAdd(&hbuf[d.w >> 8], 1);
        } else {
            for (int k = 0; k < 4; ++k)
                if (i + k < E) atomicAdd(&hbuf[edst[i + k] >> 8], 1);
        }
    }
    __syncthreads();
    for (int t = threadIdx.x; t < NB; t += 256)
        if (hbuf[t]) atomicAdd(&bucketCount[t], hbuf[t]);
}

// ---------------- k2: bucket scan -----------------------------------------
__global__ __launch_bounds__(512) void bucket_scan_kernel(
    const int* __restrict__ bucketCount, int* __restrict__ bucketStart,
    int* __restrict__ bucketCursor, int* __restrict__ row_start, int NB, int N)
{
    __shared__ int p[512];
    const int t = threadIdx.x;
    int v = (t < NB) ? bucketCount[t] : 0;
    p[t] = v;
    __syncthreads();
    for (int off = 1; off < 512; off <<= 1) {
        int u = (t >= off) ? p[t - off] : 0;
        __syncthreads();
        p[t] += u;
        __syncthreads();
    }
    if (t < NB) {
        bucketStart[t]  = p[t] - v;
        bucketCursor[t] = p[t] - v;
    }
    if (t == NB - 1) {
        bucketStart[NB] = p[t];
        row_start[N]    = p[t];   // == E
    }
}

// ---------------- k3: bin (blocks < nblkE) + proj part A ------------------
__global__ __launch_bounds__(256) void bin_proj_kernel(
    const int* __restrict__ esrc, const int* __restrict__ edst,
    int* __restrict__ bucketCursor, uint* __restrict__ binned, int E, int NB,
    int nblkE,
    const float* __restrict__ x, const ushort_t* __restrict__ wt,
    const ushort_t* __restrict__ wt2,
    ushort_t* __restrict__ feat16, float* __restrict__ el, float* __restrict__ er,
    int N)
{
    __shared__ ushort_t lds_w[144 * WROW];   // 38.25 KB (covers hist/cur too)

    if ((int)blockIdx.x >= nblkE) {
        proj_body((int)blockIdx.x - nblkE, x, wt, wt2, lds_w, feat16, el, er, N);
        return;
    }

    int* hist = (int*)lds_w;           // reuse LDS: NB_MAX ints
    int* cur  = (int*)lds_w + NB_MAX;

    const int t = threadIdx.x;
    for (int k = t; k < NB_MAX; k += 256) hist[k] = 0;
    __syncthreads();

    const int base = blockIdx.x * EPB;
    #pragma unroll
    for (int rep = 0; rep < EPB / 1024; ++rep) {
        int i = base + (rep * 256 + t) * 4;
        if (i + 3 < E) {
            int4 d = *(const int4*)(edst + i);
            atomicAdd(&hist[d.x >> 8], 1);
            atomicAdd(&hist[d.y >> 8], 1);
            atomicAdd(&hist[d.z >> 8], 1);
            atomicAdd(&hist[d.w >> 8], 1);
        } else {
            for (int k = 0; k < 4; ++k)
                if (i + k < E) atomicAdd(&hist[edst[i + k] >> 8], 1);
        }
    }
    __syncthreads();
    for (int k = t; k < NB; k += 256) {
        int hh = hist[k];
        cur[k] = hh ? atomicAdd(&bucketCursor[k], hh) : 0;
    }
    __syncthreads();
    const int nloc = min(EPB, E - base);
    for (int rep = 0; rep < EPB / 256; ++rep) {
        int idx = rep * 256 + t;
        if (idx < nloc) {
            int dv = edst[base + idx];
            int pos = atomicAdd(&cur[dv >> 8], 1);
            int src = esrc[base + idx];
            binned[pos] = (uint)src | ((uint)(dv & 255) << 24);
        }
    }
}

// ---------------- k4: fine CSR (blocks < NB) + proj part B ----------------
__global__ __launch_bounds__(256) void fine_proj_kernel(
    const uint* __restrict__ binned, const int* __restrict__ bucketStart,
    int* __restrict__ row_start, int* __restrict__ csr, int N, int NBb,
    int projOffset,
    const float* __restrict__ x, const ushort_t* __restrict__ wt,
    const ushort_t* __restrict__ wt2,
    ushort_t* __restrict__ feat16, float* __restrict__ el, float* __restrict__ er)
{
    __shared__ ushort_t lds_w[144 * WROW];

    if ((int)blockIdx.x >= NBb) {
        proj_body((int)blockIdx.x - NBb + projOffset, x, wt, wt2, lds_w, feat16, el, er, N);
        return;
    }

    int* hist = (int*)lds_w;          // 256 ints
    int* sc   = (int*)lds_w + 256;
    int* cur  = (int*)lds_w + 512;

    const int b = blockIdx.x;
    const int t = threadIdx.x;
    const int s = bucketStart[b];
    const int e = bucketStart[b + 1];

    hist[t] = 0;
    __syncthreads();
    for (int i = s + t; i < e; i += 256)
        atomicAdd(&hist[binned[i] >> 24], 1);
    __syncthreads();
    sc[t] = hist[t];
    __syncthreads();
    for (int off = 1; off < 256; off <<= 1) {
        int u = (t >= off) ? sc[t - off] : 0;
        __syncthreads();
        sc[t] += u;
        __syncthreads();
    }
    const int excl = s + sc[t] - hist[t];
    const int gn = b * NPB + t;
    if (gn < N) row_start[gn] = excl;
    cur[t] = excl;
    __syncthreads();
    for (int i = s + t; i < e; i += 256) {
        uint v = binned[i];
        int pos = atomicAdd(&cur[v >> 24], 1);
        csr[pos] = (int)(v & 0xFFFFFFu);
    }
}

// ---------------- aggregation: + setprio around compute cluster -----------
// Independent-wave pattern (like attn, m191 +4-7%): compute-phase waves win
// VALU arbitration, return to load-issue sooner. Memory path byte-identical.
__global__ __launch_bounds__(256) void aggregate_kernel(
    const u32x4* __restrict__ feat4, const float* __restrict__ el,
    const float* __restrict__ er, const int* __restrict__ row_start,
    const int* __restrict__ csr, const float* __restrict__ bias,
    float* __restrict__ out, int N)
{
    int node = blockIdx.x * 4 + (threadIdx.x >> 6);
    node = __builtin_amdgcn_readfirstlane(node);
    if (node >= N) return;
    const int lane = threadIdx.x & 63;
    const int g  = lane >> 4;        // edge slot 0..3
    const int ll = lane & 15;        // feature octet 0..15
    const int h  = ll >> 2;          // my head

    const int start = row_start[node];
    const int end   = row_start[node + 1];
    const float er_v = er[node * 4 + h];

    float rA0=0.f,rA1=0.f,rA2=0.f,rA3=0.f,rA4=0.f,rA5=0.f,rA6=0.f,rA7=0.f;
    float rB0=0.f,rB1=0.f,rB2=0.f,rB3=0.f,rB4=0.f,rB5=0.f,rB6=0.f,rB7=0.f;
    float sA = 0.f, sB = 0.f;
    const int last = end - 1;

    for (int i0 = start; i0 < end; i0 += 8) {
        const int iA = i0 + g;
        const int iB = i0 + 4 + g;
        const bool vA = iA < end;
        const bool vB = iB < end;
        const int uA = csr[vA ? iA : last];
        const int uB = csr[vB ? iB : last];
        float eA = el[uA * 4 + h];
        float eB = el[uB * 4 + h];
        u32x4 pA = feat4[(size_t)uA * 16 + ll];
        u32x4 pB = feat4[(size_t)uB * 16 + ll];

        __builtin_amdgcn_s_setprio(1);
        eA += er_v; eA = fmaxf(eA, NEG * eA);
        float xA = vA ? __expf(eA) : 0.f;
        eB += er_v; eB = fmaxf(eB, NEG * eB);
        float xB = vB ? __expf(eB) : 0.f;
        sA += xA; sB += xB;

        rA0 = fmaf(xA, __uint_as_float(pA.x << 16),         rA0);
        rA1 = fmaf(xA, __uint_as_float(pA.x & 0xffff0000u), rA1);
        rA2 = fmaf(xA, __uint_as_float(pA.y << 16),         rA2);
        rA3 = fmaf(xA, __uint_as_float(pA.y & 0xffff0000u), rA3);
        rA4 = fmaf(xA, __uint_as_float(pA.z << 16),         rA4);
        rA5 = fmaf(xA, __uint_as_float(pA.z & 0xffff0000u), rA5);
        rA6 = fmaf(xA, __uint_as_float(pA.w << 16),         rA6);
        rA7 = fmaf(xA, __uint_as_float(pA.w & 0xffff0000u), rA7);
        rB0 = fmaf(xB, __uint_as_float(pB.x << 16),         rB0);
        rB1 = fmaf(xB, __uint_as_float(pB.x & 0xffff0000u), rB1);
        rB2 = fmaf(xB, __uint_as_float(pB.y << 16),         rB2);
        rB3 = fmaf(xB, __uint_as_float(pB.y & 0xffff0000u), rB3);
        rB4 = fmaf(xB, __uint_as_float(pB.z << 16),         rB4);
        rB5 = fmaf(xB, __uint_as_float(pB.z & 0xffff0000u), rB5);
        rB6 = fmaf(xB, __uint_as_float(pB.w << 16),         rB6);
        rB7 = fmaf(xB, __uint_as_float(pB.w & 0xffff0000u), rB7);
        __builtin_amdgcn_s_setprio(0);
    }

    float r0 = rA0 + rB0, r1 = rA1 + rB1, r2 = rA2 + rB2, r3 = rA3 + rB3;
    float r4 = rA4 + rB4, r5 = rA5 + rB5, r6 = rA6 + rB6, r7 = rA7 + rB7;
    float s = sA + sB;

    s  += __shfl_xor(s, 16);  s  += __shfl_xor(s, 32);
    r0 += __shfl_xor(r0, 16); r0 += __shfl_xor(r0, 32);
    r1 += __shfl_xor(r1, 16); r1 += __shfl_xor(r1, 32);
    r2 += __shfl_xor(r2, 16); r2 += __shfl_xor(r2, 32);
    r3 += __shfl_xor(r3, 16); r3 += __shfl_xor(r3, 32);
    r4 += __shfl_xor(r4, 16); r4 += __shfl_xor(r4, 32);
    r5 += __shfl_xor(r5, 16); r5 += __shfl_xor(r5, 32);
    r6 += __shfl_xor(r6, 16); r6 += __shfl_xor(r6, 32);
    r7 += __shfl_xor(r7, 16); r7 += __shfl_xor(r7, 32);

    s = fmaxf(s, 1e-16f);
    float inv = 1.0f / s;
    r0 *= inv; r1 *= inv; r2 *= inv; r3 *= inv;
    r4 *= inv; r5 *= inv; r6 *= inv; r7 *= inv;

    r0 += __shfl_xor(r0, 4); r0 += __shfl_xor(r0, 8);
    r1 += __shfl_xor(r1, 4); r1 += __shfl_xor(r1, 8);
    r2 += __shfl_xor(r2, 4); r2 += __shfl_xor(r2, 8);
    r3 += __shfl_xor(r3, 4); r3 += __shfl_xor(r3, 8);
    r4 += __shfl_xor(r4, 4); r4 += __shfl_xor(r4, 8);
    r5 += __shfl_xor(r5, 4); r5 += __shfl_xor(r5, 8);
    r6 += __shfl_xor(r6, 4); r6 += __shfl_xor(r6, 8);
    r7 += __shfl_xor(r7, 4); r7 += __shfl_xor(r7, 8);

    if (lane < 4) {
        const int m0 = lane * 8;
        float4 o0, o1;
        o0.x = 0.25f * (r0 + bias[m0]   + bias[32+m0]   + bias[64+m0]   + bias[96+m0]);
        o0.y = 0.25f * (r1 + bias[m0+1] + bias[33+m0]   + bias[65+m0]   + bias[97+m0]);
        o0.z = 0.25f * (r2 + bias[m0+2] + bias[34+m0]   + bias[66+m0]   + bias[98+m0]);
        o0.w = 0.25f * (r3 + bias[m0+3] + bias[35+m0]   + bias[67+m0]   + bias[99+m0]);
        o1.x = 0.25f * (r4 + bias[m0+4] + bias[36+m0]   + bias[68+m0]   + bias[100+m0]);
        o1.y = 0.25f * (r5 + bias[m0+5] + bias[37+m0]   + bias[69+m0]   + bias[101+m0]);
        o1.z = 0.25f * (r6 + bias[m0+6] + bias[38+m0]   + bias[70+m0]   + bias[102+m0]);
        o1.w = 0.25f * (r7 + bias[m0+7] + bias[39+m0]   + bias[71+m0]   + bias[103+m0]);
        float* op = out + (size_t)node * 32 + m0;
        *(float4*)op       = o0;
        *(float4*)(op + 4) = o1;
    }
}

// ---------------- launch --------------------------------------------------
extern "C" void kernel_launch(void* const* d_in, const int* in_sizes, int n_in,
                              void* d_out, int out_size, void* d_ws, size_t ws_size,
                              hipStream_t stream)
{
    const float* x      = (const float*)d_in[0];
    const int*   esrc   = (const int*)  d_in[1];
    const int*   edst   = (const int*)  d_in[2];
    const float* fc_w   = (const float*)d_in[3];
    const float* attn_l = (const float*)d_in[4];
    const float* attn_r = (const float*)d_in[5];
    const float* bias   = (const float*)d_in[6];
    float* out = (float*)d_out;

    const int N = in_sizes[0] / IN_DIM;   // 100000
    const int E = in_sizes[1];            // 1600000
    const int NB = (N + NPB - 1) / NPB;   // 391

    size_t o = 0;
    char* base = (char*)d_ws;
    auto alloc = [&](size_t bytes) -> void* {
        void* p = base + o;
        o += (bytes + 255) & ~(size_t)255;
        return p;
    };
    ushort_t* feat16   = (ushort_t*)alloc((size_t)N * 128 * sizeof(ushort_t));
    float* el          = (float*)alloc((size_t)N * 4 * sizeof(float));
    float* er          = (float*)alloc((size_t)N * 4 * sizeof(float));
    int*   row_start   = (int*)  alloc(((size_t)N + 1) * sizeof(int));
    int*   csr         = (int*)  alloc((size_t)E * sizeof(int));
    uint*  binned      = (uint*) alloc((size_t)E * sizeof(uint));
    int*   bucketCount = (int*)  alloc(NB_MAX * sizeof(int));
    int*   bucketStart = (int*)  alloc((NB_MAX + 1) * sizeof(int));
    int*   bucketCursor= (int*)  alloc(NB_MAX * sizeof(int));
    ushort_t* wt       = (ushort_t*)alloc((size_t)128 * 128 * sizeof(ushort_t));
    ushort_t* wt2      = (ushort_t*)alloc((size_t)16 * 128 * sizeof(ushort_t));
    (void)ws_size;

    const int nblkE = (E + EPB - 1) / EPB;    // 196
    const int nblkP = (N + 127) / 128;        // 782 (proj blocks = 128 rows)
    // rebalance: k3's bin (~12us) > k4's fine (~8us) -> give k4 more proj
    const int projA = (nblkP * 37) / 100;     // 289 in k3
    const int projB = nblkP - projA;          // 493 in k4

    hipMemsetAsync(bucketCount, 0, NB_MAX * sizeof(int), stream);

    prep_hist_kernel<<<64 + nblkE, 256, 0, stream>>>(
        fc_w, attn_l, attn_r, wt, wt2, edst, bucketCount, E, NB);
    bucket_scan_kernel<<<1, 512, 0, stream>>>(bucketCount, bucketStart,
                                              bucketCursor, row_start, NB, N);
    bin_proj_kernel<<<nblkE + projA, 256, 0, stream>>>(
        esrc, edst, bucketCursor, binned, E, NB, nblkE,
        x, wt, wt2, feat16, el, er, N);
    fine_proj_kernel<<<NB + projB, 256, 0, stream>>>(
        binned, bucketStart, row_start, csr, N, NB, projA,
        x, wt, wt2, feat16, el, er);
    aggregate_kernel<<<(N + 3) / 4, 256, 0, stream>>>((const u32x4*)feat16, el, er,
                                                      row_start, csr, bias, out, N);
}

// Round 17
// 142.576 us; speedup vs baseline: 1.0579x; 1.0107x over previous
//
#include <hip/hip_runtime.h>

#define IN_DIM 128
#define HEADS 4
#define OUT_DIM 32
#define NEG 0.2f

#define NPB 256        // nodes per bucket (bucket = dst >> 8)
#define NB_MAX 400     // max buckets (N=100000 -> 391)
#define EPB 8192       // edges per block in hist/bin kernels

#define WROW 136       // LDS row stride in ushorts (272B: 16B-aligned, conflict-free)

typedef unsigned int uint;
typedef unsigned short ushort_t;
typedef short short8 __attribute__((ext_vector_type(8)));
typedef float f32x4 __attribute__((ext_vector_type(4)));
typedef uint u32x4 __attribute__((ext_vector_type(4)));

__device__ __forceinline__ uint bf16r(float f) {
    uint u = __float_as_uint(f);
    return (u + 0x7fffu + ((u >> 16) & 1u)) >> 16;   // RNE
}

// ---------------- proj body: 32 rows/wave, LDS-staged wt ------------------
__device__ __forceinline__ void proj_body(
    int pblk, const float* __restrict__ x, const ushort_t* __restrict__ wt,
    const ushort_t* __restrict__ wt2, ushort_t* __restrict__ lds_w,
    ushort_t* __restrict__ feat16, float* __restrict__ el, float* __restrict__ er,
    int N)
{
    // ---- stage weights: 2304 dwordx4 chunks, 9 per thread ----
    for (int q = threadIdx.x; q < 2304; q += 256) {
        const int row = q >> 4;           // 0..143
        const int ch  = q & 15;           // 16B chunk within row
        const ushort_t* src = (row < 128) ? (wt + row * 128 + ch * 8)
                                          : (wt2 + (row - 128) * 128 + ch * 8);
        *(u32x4*)(lds_w + row * WROW + ch * 8) = *(const u32x4*)src;
    }
    __syncthreads();

    const int lane = threadIdx.x & 63;
    const int w    = threadIdx.x >> 6;
    const int rowbase = pblk * 128 + w * 32;   // 32 rows per wave
    const int c = lane & 15;
    const int g = lane >> 4;

    f32x4 acc0[8], acc1[8];
    #pragma unroll
    for (int nt = 0; nt < 8; ++nt) {
        acc0[nt] = (f32x4){0.f, 0.f, 0.f, 0.f};
        acc1[nt] = (f32x4){0.f, 0.f, 0.f, 0.f};
    }
    f32x4 acc8v0 = (f32x4){0.f, 0.f, 0.f, 0.f};
    f32x4 acc8v1 = (f32x4){0.f, 0.f, 0.f, 0.f};

    const int arow0 = rowbase + c;
    const int arow1 = rowbase + 16 + c;
    const int arow0c = (arow0 < N) ? arow0 : (N - 1);
    const int arow1c = (arow1 < N) ? arow1 : (N - 1);
    const float* xrow0 = x + (size_t)arow0c * 128 + g * 8;
    const float* xrow1 = x + (size_t)arow1c * 128 + g * 8;

    #pragma unroll
    for (int kk = 0; kk < 4; ++kk) {
        float4 a0 = *(const float4*)(xrow0 + kk * 32);
        float4 a1 = *(const float4*)(xrow0 + kk * 32 + 4);
        float4 b0 = *(const float4*)(xrow1 + kk * 32);
        float4 b1 = *(const float4*)(xrow1 + kk * 32 + 4);
        u32x4 au0, au1;
        au0.x = bf16r(a0.x) | (bf16r(a0.y) << 16);
        au0.y = bf16r(a0.z) | (bf16r(a0.w) << 16);
        au0.z = bf16r(a1.x) | (bf16r(a1.y) << 16);
        au0.w = bf16r(a1.z) | (bf16r(a1.w) << 16);
        au1.x = bf16r(b0.x) | (bf16r(b0.y) << 16);
        au1.y = bf16r(b0.z) | (bf16r(b0.w) << 16);
        au1.z = bf16r(b1.x) | (bf16r(b1.y) << 16);
        au1.w = bf16r(b1.z) | (bf16r(b1.w) << 16);
        short8 afrag0 = __builtin_bit_cast(short8, au0);
        short8 afrag1 = __builtin_bit_cast(short8, au1);
        #pragma unroll
        for (int nt = 0; nt < 8; ++nt) {
            const ushort_t* wp = lds_w + (nt * 16 + c) * WROW + kk * 32 + g * 8;
            u32x4 bu = *(const u32x4*)wp;               // ds_read_b128, conflict-free
            short8 bfrag = __builtin_bit_cast(short8, bu);
            acc0[nt] = __builtin_amdgcn_mfma_f32_16x16x32_bf16(afrag0, bfrag, acc0[nt], 0, 0, 0);
            acc1[nt] = __builtin_amdgcn_mfma_f32_16x16x32_bf16(afrag1, bfrag, acc1[nt], 0, 0, 0);
        }
        {
            const ushort_t* wp2 = lds_w + (128 + c) * WROW + kk * 32 + g * 8;
            u32x4 bu2 = *(const u32x4*)wp2;
            short8 bfrag2 = __builtin_bit_cast(short8, bu2);
            acc8v0 = __builtin_amdgcn_mfma_f32_16x16x32_bf16(afrag0, bfrag2, acc8v0, 0, 0, 0);
            acc8v1 = __builtin_amdgcn_mfma_f32_16x16x32_bf16(afrag1, bfrag2, acc8v1, 0, 0, 0);
        }
    }

    #pragma unroll
    for (int r = 0; r < 4; ++r) {
        const int node0 = rowbase + g * 4 + r;
        const int node1 = rowbase + 16 + g * 4 + r;
        if (node0 < N) {
            u32x4 v;
            v.x = bf16r(acc0[0][r]) | (bf16r(acc0[1][r]) << 16);
            v.y = bf16r(acc0[2][r]) | (bf16r(acc0[3][r]) << 16);
            v.z = bf16r(acc0[4][r]) | (bf16r(acc0[5][r]) << 16);
            v.w = bf16r(acc0[6][r]) | (bf16r(acc0[7][r]) << 16);
            *(u32x4*)(feat16 + (size_t)node0 * 128 + c * 8) = v;
            if (c < 4)       el[node0 * 4 + c]       = acc8v0[r];
            else if (c < 8)  er[node0 * 4 + (c - 4)] = acc8v0[r];
        }
        if (node1 < N) {
            u32x4 v;
            v.x = bf16r(acc1[0][r]) | (bf16r(acc1[1][r]) << 16);
            v.y = bf16r(acc1[2][r]) | (bf16r(acc1[3][r]) << 16);
            v.z = bf16r(acc1[4][r]) | (bf16r(acc1[5][r]) << 16);
            v.w = bf16r(acc1[6][r]) | (bf16r(acc1[7][r]) << 16);
            *(u32x4*)(feat16 + (size_t)node1 * 128 + c * 8) = v;
            if (c < 4)       el[node1 * 4 + c]       = acc8v1[r];
            else if (c < 8)  er[node1 * 4 + (c - 4)] = acc8v1[r];
        }
    }
}

// ---------------- k1: wt prep (blocks 0..63) + coarse hist (rest) ---------
__global__ __launch_bounds__(256) void prep_hist_kernel(
    const float* __restrict__ fc_w, const float* __restrict__ attn_l,
    const float* __restrict__ attn_r,
    ushort_t* __restrict__ wt, ushort_t* __restrict__ wt2,
    const int* __restrict__ edst, int* __restrict__ bucketCount, int E, int NB)
{
    __shared__ int hbuf[NB_MAX];

    if (blockIdx.x < 64) {
        int t = blockIdx.x * 256 + threadIdx.x;   // 16384
        int n = t >> 7, k = t & 127;
        // col-permuted: row rho=nt*16+c holds W[:, 8c+nt]
        int colp = 8 * (n & 15) + (n >> 4);
        wt[t] = (ushort_t)bf16r(fc_w[k * 128 + colp]);
        if (t < 2048) {                            // 16 cols x 128 k
            int col = t >> 7;
            int kk  = t & 127;
            float ssum = 0.f;
            if (col < 8) {
                int h = col & 3;
                const float* av = (col < 4) ? attn_l : attn_r;
                #pragma unroll 8
                for (int d = 0; d < 32; ++d)
                    ssum += fc_w[kk * 128 + h * 32 + d] * av[h * 32 + d];
            }
            wt2[col * 128 + kk] = (ushort_t)bf16r(ssum);
        }
        return;
    }

    const int hblk = (int)blockIdx.x - 64;
    for (int t = threadIdx.x; t < NB_MAX; t += 256) hbuf[t] = 0;
    __syncthreads();
    const int base = hblk * EPB;
    #pragma unroll
    for (int rep = 0; rep < EPB / 1024; ++rep) {
        int i = base + (rep * 256 + threadIdx.x) * 4;
        if (i + 3 < E) {
            int4 d = *(const int4*)(edst + i);
            atomicAdd(&hbuf[d.x >> 8], 1);
            atomicAdd(&hbuf[d.y >> 8], 1);
            atomicAdd(&hbuf[d.z >> 8], 1);
            atomicAdd(&hbuf[d.w >> 8], 1);
        } else {
            for (int k = 0; k < 4; ++k)
                if (i + k < E) atomicAdd(&hbuf[edst[i + k] >> 8], 1);
        }
    }
    __syncthreads();
    for (int t = threadIdx.x; t < NB; t += 256)
        if (hbuf[t]) atomicAdd(&bucketCount[t], hbuf[t]);
}

// ---------------- k2: bucket scan -----------------------------------------
__global__ __launch_bounds__(512) void bucket_scan_kernel(
    const int* __restrict__ bucketCount, int* __restrict__ bucketStart,
    int* __restrict__ bucketCursor, int* __restrict__ row_start, int NB, int N)
{
    __shared__ int p[512];
    const int t = threadIdx.x;
    int v = (t < NB) ? bucketCount[t] : 0;
    p[t] = v;
    __syncthreads();
    for (int off = 1; off < 512; off <<= 1) {
        int u = (t >= off) ? p[t - off] : 0;
        __syncthreads();
        p[t] += u;
        __syncthreads();
    }
    if (t < NB) {
        bucketStart[t]  = p[t] - v;
        bucketCursor[t] = p[t] - v;
    }
    if (t == NB - 1) {
        bucketStart[NB] = p[t];
        row_start[N]    = p[t];   // == E
    }
}

// ---------------- k3: bin (blocks < nblkE) + proj part A ------------------
__global__ __launch_bounds__(256) void bin_proj_kernel(
    const int* __restrict__ esrc, const int* __restrict__ edst,
    int* __restrict__ bucketCursor, uint* __restrict__ binned, int E, int NB,
    int nblkE,
    const float* __restrict__ x, const ushort_t* __restrict__ wt,
    const ushort_t* __restrict__ wt2,
    ushort_t* __restrict__ feat16, float* __restrict__ el, float* __restrict__ er,
    int N)
{
    __shared__ ushort_t lds_w[144 * WROW];   // 38.25 KB (covers hist/cur too)

    if ((int)blockIdx.x >= nblkE) {
        proj_body((int)blockIdx.x - nblkE, x, wt, wt2, lds_w, feat16, el, er, N);
        return;
    }

    int* hist = (int*)lds_w;           // reuse LDS: NB_MAX ints
    int* cur  = (int*)lds_w + NB_MAX;

    const int t = threadIdx.x;
    for (int k = t; k < NB_MAX; k += 256) hist[k] = 0;
    __syncthreads();

    const int base = blockIdx.x * EPB;
    #pragma unroll
    for (int rep = 0; rep < EPB / 1024; ++rep) {
        int i = base + (rep * 256 + t) * 4;
        if (i + 3 < E) {
            int4 d = *(const int4*)(edst + i);
            atomicAdd(&hist[d.x >> 8], 1);
            atomicAdd(&hist[d.y >> 8], 1);
            atomicAdd(&hist[d.z >> 8], 1);
            atomicAdd(&hist[d.w >> 8], 1);
        } else {
            for (int k = 0; k < 4; ++k)
                if (i + k < E) atomicAdd(&hist[edst[i + k] >> 8], 1);
        }
    }
    __syncthreads();
    for (int k = t; k < NB; k += 256) {
        int hh = hist[k];
        cur[k] = hh ? atomicAdd(&bucketCursor[k], hh) : 0;
    }
    __syncthreads();
    const int nloc = min(EPB, E - base);
    for (int rep = 0; rep < EPB / 256; ++rep) {
        int idx = rep * 256 + t;
        if (idx < nloc) {
            int dv = edst[base + idx];
            int pos = atomicAdd(&cur[dv >> 8], 1);
            int src = esrc[base + idx];
            binned[pos] = (uint)src | ((uint)(dv & 255) << 24);
        }
    }
}

// ---------------- k4: fine CSR (blocks < NB) + proj part B ----------------
__global__ __launch_bounds__(256) void fine_proj_kernel(
    const uint* __restrict__ binned, const int* __restrict__ bucketStart,
    int* __restrict__ row_start, int* __restrict__ csr, int N, int NBb,
    int projOffset,
    const float* __restrict__ x, const ushort_t* __restrict__ wt,
    const ushort_t* __restrict__ wt2,
    ushort_t* __restrict__ feat16, float* __restrict__ el, float* __restrict__ er)
{
    __shared__ ushort_t lds_w[144 * WROW];

    if ((int)blockIdx.x >= NBb) {
        proj_body((int)blockIdx.x - NBb + projOffset, x, wt, wt2, lds_w, feat16, el, er, N);
        return;
    }

    int* hist = (int*)lds_w;          // 256 ints
    int* sc   = (int*)lds_w + 256;
    int* cur  = (int*)lds_w + 512;

    const int b = blockIdx.x;
    const int t = threadIdx.x;
    const int s = bucketStart[b];
    const int e = bucketStart[b + 1];

    hist[t] = 0;
    __syncthreads();
    for (int i = s + t; i < e; i += 256)
        atomicAdd(&hist[binned[i] >> 24], 1);
    __syncthreads();
    sc[t] = hist[t];
    __syncthreads();
    for (int off = 1; off < 256; off <<= 1) {
        int u = (t >= off) ? sc[t - off] : 0;
        __syncthreads();
        sc[t] += u;
        __syncthreads();
    }
    const int excl = s + sc[t] - hist[t];
    const int gn = b * NPB + t;
    if (gn < N) row_start[gn] = excl;
    cur[t] = excl;
    __syncthreads();
    for (int i = s + t; i < e; i += 256) {
        uint v = binned[i];
        int pos = atomicAdd(&cur[v >> 24], 1);
        csr[pos] = (int)(v & 0xFFFFFFu);
    }
}

// ---------------- aggregation (proven round-12 body, setprio reverted) ----
__global__ __launch_bounds__(256) void aggregate_kernel(
    const u32x4* __restrict__ feat4, const float* __restrict__ el,
    const float* __restrict__ er, const int* __restrict__ row_start,
    const int* __restrict__ csr, const float* __restrict__ bias,
    float* __restrict__ out, int N)
{
    int node = blockIdx.x * 4 + (threadIdx.x >> 6);
    node = __builtin_amdgcn_readfirstlane(node);
    if (node >= N) return;
    const int lane = threadIdx.x & 63;
    const int g  = lane >> 4;        // edge slot 0..3
    const int ll = lane & 15;        // feature octet 0..15
    const int h  = ll >> 2;          // my head

    const int start = row_start[node];
    const int end   = row_start[node + 1];
    const float er_v = er[node * 4 + h];

    float rA0=0.f,rA1=0.f,rA2=0.f,rA3=0.f,rA4=0.f,rA5=0.f,rA6=0.f,rA7=0.f;
    float rB0=0.f,rB1=0.f,rB2=0.f,rB3=0.f,rB4=0.f,rB5=0.f,rB6=0.f,rB7=0.f;
    float sA = 0.f, sB = 0.f;
    const int last = end - 1;

    for (int i0 = start; i0 < end; i0 += 8) {
        const int iA = i0 + g;
        const int iB = i0 + 4 + g;
        const bool vA = iA < end;
        const bool vB = iB < end;
        const int uA = csr[vA ? iA : last];
        const int uB = csr[vB ? iB : last];
        float eA = el[uA * 4 + h];
        float eB = el[uB * 4 + h];
        u32x4 pA = feat4[(size_t)uA * 16 + ll];
        u32x4 pB = feat4[(size_t)uB * 16 + ll];

        eA += er_v; eA = fmaxf(eA, NEG * eA);
        float xA = vA ? __expf(eA) : 0.f;
        eB += er_v; eB = fmaxf(eB, NEG * eB);
        float xB = vB ? __expf(eB) : 0.f;
        sA += xA; sB += xB;

        rA0 = fmaf(xA, __uint_as_float(pA.x << 16),         rA0);
        rA1 = fmaf(xA, __uint_as_float(pA.x & 0xffff0000u), rA1);
        rA2 = fmaf(xA, __uint_as_float(pA.y << 16),         rA2);
        rA3 = fmaf(xA, __uint_as_float(pA.y & 0xffff0000u), rA3);
        rA4 = fmaf(xA, __uint_as_float(pA.z << 16),         rA4);
        rA5 = fmaf(xA, __uint_as_float(pA.z & 0xffff0000u), rA5);
        rA6 = fmaf(xA, __uint_as_float(pA.w << 16),         rA6);
        rA7 = fmaf(xA, __uint_as_float(pA.w & 0xffff0000u), rA7);
        rB0 = fmaf(xB, __uint_as_float(pB.x << 16),         rB0);
        rB1 = fmaf(xB, __uint_as_float(pB.x & 0xffff0000u), rB1);
        rB2 = fmaf(xB, __uint_as_float(pB.y << 16),         rB2);
        rB3 = fmaf(xB, __uint_as_float(pB.y & 0xffff0000u), rB3);
        rB4 = fmaf(xB, __uint_as_float(pB.z << 16),         rB4);
        rB5 = fmaf(xB, __uint_as_float(pB.z & 0xffff0000u), rB5);
        rB6 = fmaf(xB, __uint_as_float(pB.w << 16),         rB6);
        rB7 = fmaf(xB, __uint_as_float(pB.w & 0xffff0000u), rB7);
    }

    float r0 = rA0 + rB0, r1 = rA1 + rB1, r2 = rA2 + rB2, r3 = rA3 + rB3;
    float r4 = rA4 + rB4, r5 = rA5 + rB5, r6 = rA6 + rB6, r7 = rA7 + rB7;
    float s = sA + sB;

    s  += __shfl_xor(s, 16);  s  += __shfl_xor(s, 32);
    r0 += __shfl_xor(r0, 16); r0 += __shfl_xor(r0, 32);
    r1 += __shfl_xor(r1, 16); r1 += __shfl_xor(r1, 32);
    r2 += __shfl_xor(r2, 16); r2 += __shfl_xor(r2, 32);
    r3 += __shfl_xor(r3, 16); r3 += __shfl_xor(r3, 32);
    r4 += __shfl_xor(r4, 16); r4 += __shfl_xor(r4, 32);
    r5 += __shfl_xor(r5, 16); r5 += __shfl_xor(r5, 32);
    r6 += __shfl_xor(r6, 16); r6 += __shfl_xor(r6, 32);
    r7 += __shfl_xor(r7, 16); r7 += __shfl_xor(r7, 32);

    s = fmaxf(s, 1e-16f);
    float inv = 1.0f / s;
    r0 *= inv; r1 *= inv; r2 *= inv; r3 *= inv;
    r4 *= inv; r5 *= inv; r6 *= inv; r7 *= inv;

    r0 += __shfl_xor(r0, 4); r0 += __shfl_xor(r0, 8);
    r1 += __shfl_xor(r1, 4); r1 += __shfl_xor(r1, 8);
    r2 += __shfl_xor(r2, 4); r2 += __shfl_xor(r2, 8);
    r3 += __shfl_xor(r3, 4); r3 += __shfl_xor(r3, 8);
    r4 += __shfl_xor(r4, 4); r4 += __shfl_xor(r4, 8);
    r5 += __shfl_xor(r5, 4); r5 += __shfl_xor(r5, 8);
    r6 += __shfl_xor(r6, 4); r6 += __shfl_xor(r6, 8);
    r7 += __shfl_xor(r7, 4); r7 += __shfl_xor(r7, 8);

    if (lane < 4) {
        const int m0 = lane * 8;
        float4 o0, o1;
        o0.x = 0.25f * (r0 + bias[m0]   + bias[32+m0]   + bias[64+m0]   + bias[96+m0]);
        o0.y = 0.25f * (r1 + bias[m0+1] + bias[33+m0]   + bias[65+m0]   + bias[97+m0]);
        o0.z = 0.25f * (r2 + bias[m0+2] + bias[34+m0]   + bias[66+m0]   + bias[98+m0]);
        o0.w = 0.25f * (r3 + bias[m0+3] + bias[35+m0]   + bias[67+m0]   + bias[99+m0]);
        o1.x = 0.25f * (r4 + bias[m0+4] + bias[36+m0]   + bias[68+m0]   + bias[100+m0]);
        o1.y = 0.25f * (r5 + bias[m0+5] + bias[37+m0]   + bias[69+m0]   + bias[101+m0]);
        o1.z = 0.25f * (r6 + bias[m0+6] + bias[38+m0]   + bias[70+m0]   + bias[102+m0]);
        o1.w = 0.25f * (r7 + bias[m0+7] + bias[39+m0]   + bias[71+m0]   + bias[103+m0]);
        float* op = out + (size_t)node * 32 + m0;
        *(float4*)op       = o0;
        *(float4*)(op + 4) = o1;
    }
}

// ---------------- launch --------------------------------------------------
extern "C" void kernel_launch(void* const* d_in, const int* in_sizes, int n_in,
                              void* d_out, int out_size, void* d_ws, size_t ws_size,
                              hipStream_t stream)
{
    const float* x      = (const float*)d_in[0];
    const int*   esrc   = (const int*)  d_in[1];
    const int*   edst   = (const int*)  d_in[2];
    const float* fc_w   = (const float*)d_in[3];
    const float* attn_l = (const float*)d_in[4];
    const float* attn_r = (const float*)d_in[5];
    const float* bias   = (const float*)d_in[6];
    float* out = (float*)d_out;

    const int N = in_sizes[0] / IN_DIM;   // 100000
    const int E = in_sizes[1];            // 1600000
    const int NB = (N + NPB - 1) / NPB;   // 391

    size_t o = 0;
    char* base = (char*)d_ws;
    auto alloc = [&](size_t bytes) -> void* {
        void* p = base + o;
        o += (bytes + 255) & ~(size_t)255;
        return p;
    };
    ushort_t* feat16   = (ushort_t*)alloc((size_t)N * 128 * sizeof(ushort_t));
    float* el          = (float*)alloc((size_t)N * 4 * sizeof(float));
    float* er          = (float*)alloc((size_t)N * 4 * sizeof(float));
    int*   row_start   = (int*)  alloc(((size_t)N + 1) * sizeof(int));
    int*   csr         = (int*)  alloc((size_t)E * sizeof(int));
    uint*  binned      = (uint*) alloc((size_t)E * sizeof(uint));
    int*   bucketCount = (int*)  alloc(NB_MAX * sizeof(int));
    int*   bucketStart = (int*)  alloc((NB_MAX + 1) * sizeof(int));
    int*   bucketCursor= (int*)  alloc(NB_MAX * sizeof(int));
    ushort_t* wt       = (ushort_t*)alloc((size_t)128 * 128 * sizeof(ushort_t));
    ushort_t* wt2      = (ushort_t*)alloc((size_t)16 * 128 * sizeof(ushort_t));
    (void)ws_size;

    const int nblkE = (E + EPB - 1) / EPB;    // 196
    const int nblkP = (N + 127) / 128;        // 782 (proj blocks = 128 rows)
    const int projA = (nblkP * 37) / 100;     // 289 in k3 (balances bin > fine)
    const int projB = nblkP - projA;          // 493 in k4

    hipMemsetAsync(bucketCount, 0, NB_MAX * sizeof(int), stream);

    prep_hist_kernel<<<64 + nblkE, 256, 0, stream>>>(
        fc_w, attn_l, attn_r, wt, wt2, edst, bucketCount, E, NB);
    bucket_scan_kernel<<<1, 512, 0, stream>>>(bucketCount, bucketStart,
                                              bucketCursor, row_start, NB, N);
    bin_proj_kernel<<<nblkE + projA, 256, 0, stream>>>(
        esrc, edst, bucketCursor, binned, E, NB, nblkE,
        x, wt, wt2, feat16, el, er, N);
    fine_proj_kernel<<<NB + projB, 256, 0, stream>>>(
        binned, bucketStart, row_start, csr, N, NB, projA,
        x, wt, wt2, feat16, el, er);
    aggregate_kernel<<<(N + 3) / 4, 256, 0, stream>>>((const u32x4*)feat16, el, er,
                                                      row_start, csr, bias, out, N);
}